// Round 1
// baseline (969.335 us; speedup 1.0000x reference)
//
#include <hip/hip_runtime.h>
#include <hip/hip_bf16.h>
#include <math.h>

#define NEG_SLOPE 0.2f

// ---------------------------------------------------------------- CSR build
__global__ void degree_kernel(const int* __restrict__ ei, int E, int n,
                              int* __restrict__ deg) {
    int e = blockIdx.x * 256 + threadIdx.x;
    int tot = E + n;
    if (e >= tot) return;
    int d = (e < E) ? ei[E + e] : (e - E);
    atomicAdd(&deg[d], 1);
}

__global__ __launch_bounds__(1024) void scan_kernel(const int* __restrict__ deg,
                                                    int* __restrict__ row_off, int n) {
    __shared__ int tmp[1024];
    __shared__ int carry_s;
    int t = threadIdx.x;
    if (t == 0) carry_s = 0;
    __syncthreads();
    for (int base = 0; base < n; base += 1024) {
        int idx = base + t;
        int v = (idx < n) ? deg[idx] : 0;
        int carry = carry_s;
        tmp[t] = v;
        __syncthreads();
        #pragma unroll
        for (int off = 1; off < 1024; off <<= 1) {
            int x = (t >= off) ? tmp[t - off] : 0;
            __syncthreads();
            tmp[t] += x;
            __syncthreads();
        }
        int incl = tmp[t];
        if (idx < n) row_off[idx] = carry + incl - v;
        __syncthreads();
        if (t == 0) carry_s = carry + tmp[1023];
        __syncthreads();
    }
    if (t == 0) row_off[n] = carry_s;
}

__global__ void copy_kernel(const int* __restrict__ src, int* __restrict__ dst, int n) {
    int i = blockIdx.x * 256 + threadIdx.x;
    if (i < n) dst[i] = src[i];
}

__global__ void scatter_kernel(const int* __restrict__ ei, int E, int n,
                               int* __restrict__ cursor, int* __restrict__ csr_src) {
    int e = blockIdx.x * 256 + threadIdx.x;
    int tot = E + n;
    if (e >= tot) return;
    int s, d;
    if (e < E) { s = ei[e]; d = ei[E + e]; } else { s = d = e - E; }
    int pos = atomicAdd(&cursor[d], 1);
    csr_src[pos] = s;
}

// ---------------------------------------------------------------- fp32 GEMM
// C[M,N] = A[M,K] @ B[K,N], row-major. BM=BN=128, BK=16, 256 thr, 8x8 micro.
__global__ __launch_bounds__(256) void gemm_kernel(const float* __restrict__ A,
                                                   const float* __restrict__ B,
                                                   float* __restrict__ C,
                                                   int M, int N, int K) {
    __shared__ float As[16][132];
    __shared__ float Bs[16][128];
    int t = threadIdx.x;
    int row0 = blockIdx.x * 128;
    int col0 = blockIdx.y * 128;
    int tr = (t >> 4) * 8;
    int tc = (t & 15) * 8;
    float acc[8][8] = {};
    for (int k0 = 0; k0 < K; k0 += 16) {
        #pragma unroll
        for (int i = 0; i < 2; i++) {
            int f = t + i * 256;          // float4 slot 0..511
            int m = f >> 2;               // 0..127
            int kg = (f & 3) * 4;
            int grow = row0 + m;
            float4 v = make_float4(0.f, 0.f, 0.f, 0.f);
            if (grow < M) v = *(const float4*)(A + (size_t)grow * K + k0 + kg);
            As[kg + 0][m] = v.x; As[kg + 1][m] = v.y;
            As[kg + 2][m] = v.z; As[kg + 3][m] = v.w;
        }
        #pragma unroll
        for (int i = 0; i < 2; i++) {
            int f = t + i * 256;
            int kk = f >> 5;              // 0..15
            int c = (f & 31) * 4;
            int gc = col0 + c;
            float4 v = make_float4(0.f, 0.f, 0.f, 0.f);
            if (gc + 3 < N) {
                v = *(const float4*)(B + (size_t)(k0 + kk) * N + gc);
            } else {
                float tv[4] = {0.f, 0.f, 0.f, 0.f};
                for (int j = 0; j < 4; j++)
                    if (gc + j < N) tv[j] = B[(size_t)(k0 + kk) * N + gc + j];
                v = make_float4(tv[0], tv[1], tv[2], tv[3]);
            }
            *(float4*)&Bs[kk][c] = v;
        }
        __syncthreads();
        #pragma unroll
        for (int kk = 0; kk < 16; kk++) {
            float a[8], b[8];
            *(float4*)&a[0] = *(const float4*)&As[kk][tr];
            *(float4*)&a[4] = *(const float4*)&As[kk][tr + 4];
            *(float4*)&b[0] = *(const float4*)&Bs[kk][tc];
            *(float4*)&b[4] = *(const float4*)&Bs[kk][tc + 4];
            #pragma unroll
            for (int i = 0; i < 8; i++)
                #pragma unroll
                for (int j = 0; j < 8; j++)
                    acc[i][j] = fmaf(a[i], b[j], acc[i][j]);
        }
        __syncthreads();
    }
    for (int i = 0; i < 8; i++) {
        int r = row0 + tr + i;
        if (r >= M) continue;
        for (int j = 0; j < 8; j += 4) {
            int c = col0 + tc + j;
            if (c + 3 < N) {
                *(float4*)(C + (size_t)r * N + c) =
                    make_float4(acc[i][j], acc[i][j + 1], acc[i][j + 2], acc[i][j + 3]);
            } else {
                for (int jj = 0; jj < 4; jj++)
                    if (c + jj < N) C[(size_t)r * N + c + jj] = acc[i][j + jj];
            }
        }
    }
}

// ---------------------------------------------------------------- attention coefs
// als[n][h] = sum_c h[n][h][c]*a_src[h][c]; ald likewise. One wave per node.
template <int C>
__global__ __launch_bounds__(256) void coef_kernel(const float* __restrict__ h,
                                                   const float* __restrict__ a_src,
                                                   const float* __restrict__ a_dst,
                                                   float* __restrict__ als,
                                                   float* __restrict__ ald, int n) {
    int wave = threadIdx.x >> 6;
    int lane = threadIdx.x & 63;
    int node = blockIdx.x * 4 + wave;
    if (node >= n) return;
    const float* hr = h + (size_t)node * (4 * C);
    float ps[4], pd[4];
    #pragma unroll
    for (int hh = 0; hh < 4; hh++) {
        float hv = (lane < C) ? hr[hh * C + lane] : 0.f;
        float as_ = (lane < C) ? a_src[hh * C + lane] : 0.f;
        float ad_ = (lane < C) ? a_dst[hh * C + lane] : 0.f;
        ps[hh] = hv * as_;
        pd[hh] = hv * ad_;
    }
    #pragma unroll
    for (int off = 32; off >= 1; off >>= 1) {
        #pragma unroll
        for (int hh = 0; hh < 4; hh++) {
            ps[hh] += __shfl_xor(ps[hh], off, 64);
            pd[hh] += __shfl_xor(pd[hh], off, 64);
        }
    }
    if (lane == 0) {
        #pragma unroll
        for (int hh = 0; hh < 4; hh++) {
            als[node * 4 + hh] = ps[hh];
            ald[node * 4 + hh] = pd[hh];
        }
    }
}

// ---------------------------------------------------------------- aggregation
// MODE 0: out = elu(v + bias)          (layer 1 -> x1)
// MODE 1: out = elu(v + bias + res)    (layer 2 -> x2)
// MODE 2: out = mean_h(v) + bias       (layer 3 -> d_out), C=40
template <int C, int MODE>
__global__ __launch_bounds__(256) void agg_kernel(const float* __restrict__ hfeat,
                                                  const float* __restrict__ als,
                                                  const float* __restrict__ ald,
                                                  const int* __restrict__ row_off,
                                                  const int* __restrict__ csr_src,
                                                  const float* __restrict__ bias,
                                                  const float* __restrict__ res,
                                                  float* __restrict__ out, int n) {
    int wave = threadIdx.x >> 6;
    int lane = threadIdx.x & 63;
    int node = blockIdx.x * 4 + wave;
    if (node >= n) return;
    int rs = row_off[node];
    int re = row_off[node + 1];
    float aldn[4];
    #pragma unroll
    for (int hh = 0; hh < 4; hh++) aldn[hh] = ald[node * 4 + hh];

    // pass 1: segment max per head (lanes split edges)
    float m[4] = {-INFINITY, -INFINITY, -INFINITY, -INFINITY};
    for (int i = rs + lane; i < re; i += 64) {
        int s = csr_src[i];
        #pragma unroll
        for (int hh = 0; hh < 4; hh++) {
            float l = als[s * 4 + hh] + aldn[hh];
            l = (l > 0.f) ? l : NEG_SLOPE * l;
            m[hh] = fmaxf(m[hh], l);
        }
    }
    #pragma unroll
    for (int off = 32; off >= 1; off >>= 1)
        #pragma unroll
        for (int hh = 0; hh < 4; hh++)
            m[hh] = fmaxf(m[hh], __shfl_xor(m[hh], off, 64));

    // pass 2: accumulate exp-weighted messages (serial over edges, lane = channel)
    float den[4] = {0.f, 0.f, 0.f, 0.f};
    float acc[4] = {0.f, 0.f, 0.f, 0.f};
    for (int i = rs; i < re; ++i) {
        int s = csr_src[i];
        const float* hr = hfeat + (size_t)s * (4 * C);
        #pragma unroll
        for (int hh = 0; hh < 4; hh++) {
            float l = als[s * 4 + hh] + aldn[hh];
            l = (l > 0.f) ? l : NEG_SLOPE * l;
            float ex = __expf(l - m[hh]);
            den[hh] += ex;
            float hv = (lane < C) ? hr[hh * C + lane] : 0.f;
            acc[hh] = fmaf(ex, hv, acc[hh]);
        }
    }

    if (MODE == 2) {
        if (lane < C) {
            float v = 0.f;
            #pragma unroll
            for (int hh = 0; hh < 4; hh++) v += acc[hh] / (den[hh] + 1e-16f);
            v = v * 0.25f + bias[lane];
            out[(size_t)node * C + lane] = v;
        }
    } else {
        #pragma unroll
        for (int hh = 0; hh < 4; hh++) {
            float v = acc[hh] / (den[hh] + 1e-16f);
            size_t idx = (size_t)node * (4 * C) + hh * C + lane;
            float o = v + bias[hh * C + lane];
            if (MODE == 1) o += res[idx];
            o = (o > 0.f) ? o : expm1f(o);
            out[idx] = o;
        }
    }
}

// ---------------------------------------------------------------- launch
extern "C" void kernel_launch(void* const* d_in, const int* in_sizes, int n_in,
                              void* d_out, int out_size, void* d_ws, size_t ws_size,
                              hipStream_t stream) {
    const float* x   = (const float*)d_in[0];
    const int*   ei  = (const int*)d_in[1];
    const float* W1  = (const float*)d_in[2];
    const float* a1s = (const float*)d_in[3];
    const float* a1d = (const float*)d_in[4];
    const float* b1  = (const float*)d_in[5];
    const float* W2  = (const float*)d_in[6];
    const float* a2s = (const float*)d_in[7];
    const float* a2d = (const float*)d_in[8];
    const float* b2  = (const float*)d_in[9];
    const float* W3  = (const float*)d_in[10];
    const float* a3s = (const float*)d_in[11];
    const float* a3d = (const float*)d_in[12];
    const float* b3  = (const float*)d_in[13];
    float* out = (float*)d_out;

    int N = in_sizes[0] / 128;
    int E = in_sizes[1] / 2;

    char* ws = (char*)d_ws;
    size_t off = 0;
    auto alloc = [&](size_t bytes) -> void* {
        void* p = ws + off;
        off += (bytes + 255) & ~(size_t)255;
        return p;
    };
    float* hbuf = (float*)alloc((size_t)N * 256 * 4);
    float* x1   = (float*)alloc((size_t)N * 256 * 4);
    float* x2   = (float*)alloc((size_t)N * 256 * 4);
    float* als  = (float*)alloc((size_t)N * 4 * 4);
    float* ald  = (float*)alloc((size_t)N * 4 * 4);
    int* deg     = (int*)alloc((size_t)N * 4);
    int* row_off = (int*)alloc((size_t)(N + 1) * 4);
    int* cursor  = (int*)alloc((size_t)N * 4);
    int* csr     = (int*)alloc((size_t)(E + N) * 4);

    int tot = E + N;
    hipMemsetAsync(deg, 0, (size_t)N * 4, stream);
    degree_kernel<<<(tot + 255) / 256, 256, 0, stream>>>(ei, E, N, deg);
    scan_kernel<<<1, 1024, 0, stream>>>(deg, row_off, N);
    copy_kernel<<<(N + 255) / 256, 256, 0, stream>>>(row_off, cursor, N);
    scatter_kernel<<<(tot + 255) / 256, 256, 0, stream>>>(ei, E, N, cursor, csr);

    int nodeBlocks = (N + 3) / 4;
    dim3 blk(256);

    // layer 1
    {
        dim3 grid((N + 127) / 128, 2);
        gemm_kernel<<<grid, blk, 0, stream>>>(x, W1, hbuf, N, 256, 128);
        coef_kernel<64><<<nodeBlocks, blk, 0, stream>>>(hbuf, a1s, a1d, als, ald, N);
        agg_kernel<64, 0><<<nodeBlocks, blk, 0, stream>>>(hbuf, als, ald, row_off, csr,
                                                          b1, nullptr, x1, N);
    }
    // layer 2
    {
        dim3 grid((N + 127) / 128, 2);
        gemm_kernel<<<grid, blk, 0, stream>>>(x1, W2, hbuf, N, 256, 256);
        coef_kernel<64><<<nodeBlocks, blk, 0, stream>>>(hbuf, a2s, a2d, als, ald, N);
        agg_kernel<64, 1><<<nodeBlocks, blk, 0, stream>>>(hbuf, als, ald, row_off, csr,
                                                          b2, x1, x2, N);
    }
    // layer 3
    {
        dim3 grid((N + 127) / 128, 2);
        gemm_kernel<<<grid, blk, 0, stream>>>(x2, W3, hbuf, N, 160, 256);
        coef_kernel<40><<<nodeBlocks, blk, 0, stream>>>(hbuf, a3s, a3d, als, ald, N);
        agg_kernel<40, 2><<<nodeBlocks, blk, 0, stream>>>(hbuf, als, ald, row_off, csr,
                                                          b3, nullptr, out, N);
    }
}

// Round 2
// 783.168 us; speedup vs baseline: 1.2377x; 1.2377x over previous
//
#include <hip/hip_runtime.h>
#include <hip/hip_bf16.h>
#include <math.h>

#define NEG_SLOPE 0.2f

// ---------------------------------------------------------------- CSR build
__global__ void degree_kernel(const int* __restrict__ ei, int E, int n,
                              int* __restrict__ deg) {
    int e = blockIdx.x * 256 + threadIdx.x;
    int tot = E + n;
    if (e >= tot) return;
    int d = (e < E) ? ei[E + e] : (e - E);
    atomicAdd(&deg[d], 1);
}

// hierarchical exclusive scan: phase 1 — per-block (1024) local scan + block sums
__global__ __launch_bounds__(1024) void scan_block(const int* __restrict__ deg,
                                                   int* __restrict__ row_off,
                                                   int* __restrict__ bsums, int n) {
    __shared__ int tmp[1024];
    int t = threadIdx.x;
    int idx = blockIdx.x * 1024 + t;
    int v = (idx < n) ? deg[idx] : 0;
    tmp[t] = v;
    __syncthreads();
    #pragma unroll
    for (int off = 1; off < 1024; off <<= 1) {
        int x = (t >= off) ? tmp[t - off] : 0;
        __syncthreads();
        tmp[t] += x;
        __syncthreads();
    }
    if (idx < n) row_off[idx] = tmp[t] - v;   // exclusive within block
    if (t == 1023) bsums[blockIdx.x] = tmp[1023];
}

// phase 2 — scan block sums (single wave, handles nb>64 via carry loop)
__global__ __launch_bounds__(64) void scan_sums(int* __restrict__ bsums, int nb,
                                                int* __restrict__ row_off, int n) {
    int lane = threadIdx.x;
    int carry = 0;
    for (int base = 0; base < nb; base += 64) {
        int i = base + lane;
        int o = (i < nb) ? bsums[i] : 0;
        int v = o;
        #pragma unroll
        for (int off = 1; off < 64; off <<= 1) {
            int x = __shfl_up(v, off, 64);
            if (lane >= off) v += x;
        }
        if (i < nb) bsums[i] = carry + v - o;   // exclusive
        int tot = __shfl(v, 63, 64);
        carry += tot;
    }
    if (lane == 0) row_off[n] = carry;
}

// phase 3 — add block offsets, and init cursor copy
__global__ __launch_bounds__(1024) void scan_add(int* __restrict__ row_off,
                                                 const int* __restrict__ bsums,
                                                 int* __restrict__ cursor, int n) {
    int idx = blockIdx.x * 1024 + threadIdx.x;
    if (idx < n) {
        int v = row_off[idx] + bsums[blockIdx.x];
        row_off[idx] = v;
        cursor[idx] = v;
    }
}

__global__ void scatter_kernel(const int* __restrict__ ei, int E, int n,
                               int* __restrict__ cursor, int* __restrict__ csr_src) {
    int e = blockIdx.x * 256 + threadIdx.x;
    int tot = E + n;
    if (e >= tot) return;
    int s, d;
    if (e < E) { s = ei[e]; d = ei[E + e]; } else { s = d = e - E; }
    int pos = atomicAdd(&cursor[d], 1);
    csr_src[pos] = s;
}

// ---------------------------------------------------------------- fp32 GEMM
// C[M,N] = A[M,K] @ B[K,N], row-major. BM=BN=128, BK=16, 256 thr, 8x8 micro.
__global__ __launch_bounds__(256) void gemm_kernel(const float* __restrict__ A,
                                                   const float* __restrict__ B,
                                                   float* __restrict__ C,
                                                   int M, int N, int K) {
    __shared__ float As[16][132];
    __shared__ float Bs[16][128];
    int t = threadIdx.x;
    int row0 = blockIdx.x * 128;
    int col0 = blockIdx.y * 128;
    int tr = (t >> 4) * 8;
    int tc = (t & 15) * 8;
    float acc[8][8] = {};
    for (int k0 = 0; k0 < K; k0 += 16) {
        #pragma unroll
        for (int i = 0; i < 2; i++) {
            int f = t + i * 256;          // float4 slot 0..511
            int m = f >> 2;               // 0..127
            int kg = (f & 3) * 4;
            int grow = row0 + m;
            float4 v = make_float4(0.f, 0.f, 0.f, 0.f);
            if (grow < M) v = *(const float4*)(A + (size_t)grow * K + k0 + kg);
            As[kg + 0][m] = v.x; As[kg + 1][m] = v.y;
            As[kg + 2][m] = v.z; As[kg + 3][m] = v.w;
        }
        #pragma unroll
        for (int i = 0; i < 2; i++) {
            int f = t + i * 256;
            int kk = f >> 5;              // 0..15
            int c = (f & 31) * 4;
            int gc = col0 + c;
            float4 v = make_float4(0.f, 0.f, 0.f, 0.f);
            if (gc + 3 < N) {
                v = *(const float4*)(B + (size_t)(k0 + kk) * N + gc);
            } else {
                float tv[4] = {0.f, 0.f, 0.f, 0.f};
                for (int j = 0; j < 4; j++)
                    if (gc + j < N) tv[j] = B[(size_t)(k0 + kk) * N + gc + j];
                v = make_float4(tv[0], tv[1], tv[2], tv[3]);
            }
            *(float4*)&Bs[kk][c] = v;
        }
        __syncthreads();
        #pragma unroll
        for (int kk = 0; kk < 16; kk++) {
            float a[8], b[8];
            *(float4*)&a[0] = *(const float4*)&As[kk][tr];
            *(float4*)&a[4] = *(const float4*)&As[kk][tr + 4];
            *(float4*)&b[0] = *(const float4*)&Bs[kk][tc];
            *(float4*)&b[4] = *(const float4*)&Bs[kk][tc + 4];
            #pragma unroll
            for (int i = 0; i < 8; i++)
                #pragma unroll
                for (int j = 0; j < 8; j++)
                    acc[i][j] = fmaf(a[i], b[j], acc[i][j]);
        }
        __syncthreads();
    }
    for (int i = 0; i < 8; i++) {
        int r = row0 + tr + i;
        if (r >= M) continue;
        for (int j = 0; j < 8; j += 4) {
            int c = col0 + tc + j;
            if (c + 3 < N) {
                *(float4*)(C + (size_t)r * N + c) =
                    make_float4(acc[i][j], acc[i][j + 1], acc[i][j + 2], acc[i][j + 3]);
            } else {
                for (int jj = 0; jj < 4; jj++)
                    if (c + jj < N) C[(size_t)r * N + c + jj] = acc[i][j + jj];
            }
        }
    }
}

// ---------------------------------------------------------------- attention coefs
template <int C>
__global__ __launch_bounds__(256) void coef_kernel(const float* __restrict__ h,
                                                   const float* __restrict__ a_src,
                                                   const float* __restrict__ a_dst,
                                                   float* __restrict__ als,
                                                   float* __restrict__ ald, int n) {
    int wave = threadIdx.x >> 6;
    int lane = threadIdx.x & 63;
    int node = blockIdx.x * 4 + wave;
    if (node >= n) return;
    const float* hr = h + (size_t)node * (4 * C);
    float ps[4], pd[4];
    #pragma unroll
    for (int hh = 0; hh < 4; hh++) {
        float hv = (lane < C) ? hr[hh * C + lane] : 0.f;
        float as_ = (lane < C) ? a_src[hh * C + lane] : 0.f;
        float ad_ = (lane < C) ? a_dst[hh * C + lane] : 0.f;
        ps[hh] = hv * as_;
        pd[hh] = hv * ad_;
    }
    #pragma unroll
    for (int off = 32; off >= 1; off >>= 1) {
        #pragma unroll
        for (int hh = 0; hh < 4; hh++) {
            ps[hh] += __shfl_xor(ps[hh], off, 64);
            pd[hh] += __shfl_xor(pd[hh], off, 64);
        }
    }
    if (lane == 0) {
        #pragma unroll
        for (int hh = 0; hh < 4; hh++) {
            als[node * 4 + hh] = ps[hh];
            ald[node * 4 + hh] = pd[hh];
        }
    }
}

// ---------------------------------------------------------------- aggregation
// lane owns 4 consecutive channels of ONE head (float4 at byte offset lane*16).
// ex computed lane-parallel per 64-edge chunk, broadcast via wave-private LDS.
// MODE 0: out = elu(v + bias)       MODE 1: out = elu(v + bias + res)
// MODE 2: out = mean_h(v) + bias    (C=40 -> d_out)
template <int C, int MODE>
__global__ __launch_bounds__(256) void agg_kernel(const float* __restrict__ hfeat,
                                                  const float* __restrict__ als,
                                                  const float* __restrict__ ald,
                                                  const int* __restrict__ row_off,
                                                  const int* __restrict__ csr_src,
                                                  const float* __restrict__ bias,
                                                  const float* __restrict__ res,
                                                  float* __restrict__ out, int n) {
    constexpr int HC = 4 * C;        // floats per h row
    constexpr int LPN = HC / 4;      // active lanes for accumulate (64 or 40)
    constexpr int LPH = C / 4;       // lanes per head (16 or 10)
    __shared__ float ex_lds[4][64][4];
    __shared__ int s_lds[4][64];

    int wave = threadIdx.x >> 6;
    int lane = threadIdx.x & 63;
    int node = blockIdx.x * 4 + wave;
    if (node >= n) return;
    int rs = row_off[node];
    int re = row_off[node + 1];
    float4 ald4 = *(const float4*)(ald + (size_t)node * 4);

    int g = lane / LPH;              // head this lane accumulates for
    if (g > 3) g = 3;

    // ---- pass 1: per-head segment max (lane-parallel over edges)
    float m0 = -INFINITY, m1 = -INFINITY, m2 = -INFINITY, m3 = -INFINITY;
    for (int i = rs + lane; i < re; i += 64) {
        int s = csr_src[i];
        float4 a = *(const float4*)(als + (size_t)s * 4);
        float l0 = a.x + ald4.x; l0 = (l0 > 0.f) ? l0 : NEG_SLOPE * l0;
        float l1 = a.y + ald4.y; l1 = (l1 > 0.f) ? l1 : NEG_SLOPE * l1;
        float l2 = a.z + ald4.z; l2 = (l2 > 0.f) ? l2 : NEG_SLOPE * l2;
        float l3 = a.w + ald4.w; l3 = (l3 > 0.f) ? l3 : NEG_SLOPE * l3;
        m0 = fmaxf(m0, l0); m1 = fmaxf(m1, l1);
        m2 = fmaxf(m2, l2); m3 = fmaxf(m3, l3);
    }
    #pragma unroll
    for (int off = 32; off >= 1; off >>= 1) {
        m0 = fmaxf(m0, __shfl_xor(m0, off, 64));
        m1 = fmaxf(m1, __shfl_xor(m1, off, 64));
        m2 = fmaxf(m2, __shfl_xor(m2, off, 64));
        m3 = fmaxf(m3, __shfl_xor(m3, off, 64));
    }

    // ---- pass 2: chunks of 64 edges: ex lane-parallel -> LDS -> fma accumulate
    float4 acc = make_float4(0.f, 0.f, 0.f, 0.f);
    float d0 = 0.f, d1 = 0.f, d2 = 0.f, d3 = 0.f;
    for (int chunk = rs; chunk < re; chunk += 64) {
        int eid = chunk + lane;
        float e0 = 0.f, e1 = 0.f, e2 = 0.f, e3 = 0.f;
        int s = 0;
        if (eid < re) {
            s = csr_src[eid];
            float4 a = *(const float4*)(als + (size_t)s * 4);
            float l0 = a.x + ald4.x; l0 = (l0 > 0.f) ? l0 : NEG_SLOPE * l0;
            float l1 = a.y + ald4.y; l1 = (l1 > 0.f) ? l1 : NEG_SLOPE * l1;
            float l2 = a.z + ald4.z; l2 = (l2 > 0.f) ? l2 : NEG_SLOPE * l2;
            float l3 = a.w + ald4.w; l3 = (l3 > 0.f) ? l3 : NEG_SLOPE * l3;
            e0 = __expf(l0 - m0); e1 = __expf(l1 - m1);
            e2 = __expf(l2 - m2); e3 = __expf(l3 - m3);
            d0 += e0; d1 += e1; d2 += e2; d3 += e3;
        }
        s_lds[wave][lane] = s;
        *(float4*)&ex_lds[wave][lane][0] = make_float4(e0, e1, e2, e3);
        asm volatile("s_waitcnt lgkmcnt(0)" ::: "memory");  // wave-internal LDS visibility
        int nv = re - chunk; if (nv > 64) nv = 64;
        if (lane < LPN) {
            #pragma unroll 2
            for (int j = 0; j < nv; ++j) {
                int sj = s_lds[wave][j];
                float exg = ex_lds[wave][j][g];
                float4 hv = *(const float4*)(hfeat + (size_t)sj * HC + lane * 4);
                acc.x = fmaf(exg, hv.x, acc.x);
                acc.y = fmaf(exg, hv.y, acc.y);
                acc.z = fmaf(exg, hv.z, acc.z);
                acc.w = fmaf(exg, hv.w, acc.w);
            }
        }
    }
    // reduce denominators across wave
    #pragma unroll
    for (int off = 32; off >= 1; off >>= 1) {
        d0 += __shfl_xor(d0, off, 64);
        d1 += __shfl_xor(d1, off, 64);
        d2 += __shfl_xor(d2, off, 64);
        d3 += __shfl_xor(d3, off, 64);
    }
    float dg = (g == 0) ? d0 : (g == 1) ? d1 : (g == 2) ? d2 : d3;
    float inv = 1.f / (dg + 1e-16f);
    float4 v = make_float4(acc.x * inv, acc.y * inv, acc.z * inv, acc.w * inv);

    if (MODE == 2) {
        // mean over heads: channel c lives in lanes lane%LPH + k*LPH, k=0..3
        float4 vs = v;
        #pragma unroll
        for (int k = 1; k < 4; k++) {
            int srcl = lane + k * LPH;
            vs.x += __shfl(v.x, srcl, 64);
            vs.y += __shfl(v.y, srcl, 64);
            vs.z += __shfl(v.z, srcl, 64);
            vs.w += __shfl(v.w, srcl, 64);
        }
        if (lane < LPH) {
            float4 b4 = *(const float4*)(bias + lane * 4);
            float4 o = make_float4(vs.x * 0.25f + b4.x, vs.y * 0.25f + b4.y,
                                   vs.z * 0.25f + b4.z, vs.w * 0.25f + b4.w);
            *(float4*)(out + (size_t)node * C + lane * 4) = o;
        }
    } else {
        if (lane < LPN) {
            float4 b4 = *(const float4*)(bias + lane * 4);
            float4 o = make_float4(v.x + b4.x, v.y + b4.y, v.z + b4.z, v.w + b4.w);
            if (MODE == 1) {
                float4 r4 = *(const float4*)(res + (size_t)node * HC + lane * 4);
                o.x += r4.x; o.y += r4.y; o.z += r4.z; o.w += r4.w;
            }
            o.x = (o.x > 0.f) ? o.x : expm1f(o.x);
            o.y = (o.y > 0.f) ? o.y : expm1f(o.y);
            o.z = (o.z > 0.f) ? o.z : expm1f(o.z);
            o.w = (o.w > 0.f) ? o.w : expm1f(o.w);
            *(float4*)(out + (size_t)node * HC + lane * 4) = o;
        }
    }
}

// ---------------------------------------------------------------- launch
extern "C" void kernel_launch(void* const* d_in, const int* in_sizes, int n_in,
                              void* d_out, int out_size, void* d_ws, size_t ws_size,
                              hipStream_t stream) {
    const float* x   = (const float*)d_in[0];
    const int*   ei  = (const int*)d_in[1];
    const float* W1  = (const float*)d_in[2];
    const float* a1s = (const float*)d_in[3];
    const float* a1d = (const float*)d_in[4];
    const float* b1  = (const float*)d_in[5];
    const float* W2  = (const float*)d_in[6];
    const float* a2s = (const float*)d_in[7];
    const float* a2d = (const float*)d_in[8];
    const float* b2  = (const float*)d_in[9];
    const float* W3  = (const float*)d_in[10];
    const float* a3s = (const float*)d_in[11];
    const float* a3d = (const float*)d_in[12];
    const float* b3  = (const float*)d_in[13];
    float* out = (float*)d_out;

    int N = in_sizes[0] / 128;
    int E = in_sizes[1] / 2;

    char* ws = (char*)d_ws;
    size_t off = 0;
    auto alloc = [&](size_t bytes) -> void* {
        void* p = ws + off;
        off += (bytes + 255) & ~(size_t)255;
        return p;
    };
    float* hbuf = (float*)alloc((size_t)N * 256 * 4);
    float* x1   = (float*)alloc((size_t)N * 256 * 4);
    float* x2   = (float*)alloc((size_t)N * 256 * 4);
    float* als  = (float*)alloc((size_t)N * 4 * 4);
    float* ald  = (float*)alloc((size_t)N * 4 * 4);
    int* deg     = (int*)alloc((size_t)N * 4);
    int* row_off = (int*)alloc((size_t)(N + 1) * 4);
    int* cursor  = (int*)alloc((size_t)N * 4);
    int* csr     = (int*)alloc((size_t)(E + N) * 4);
    int* bsums   = (int*)alloc(1024 * 4);

    int tot = E + N;
    int nb = (N + 1023) / 1024;
    hipMemsetAsync(deg, 0, (size_t)N * 4, stream);
    degree_kernel<<<(tot + 255) / 256, 256, 0, stream>>>(ei, E, N, deg);
    scan_block<<<nb, 1024, 0, stream>>>(deg, row_off, bsums, N);
    scan_sums<<<1, 64, 0, stream>>>(bsums, nb, row_off, N);
    scan_add<<<nb, 1024, 0, stream>>>(row_off, bsums, cursor, N);
    scatter_kernel<<<(tot + 255) / 256, 256, 0, stream>>>(ei, E, N, cursor, csr);

    int nodeBlocks = (N + 3) / 4;
    dim3 blk(256);

    // layer 1
    {
        dim3 grid((N + 127) / 128, 2);
        gemm_kernel<<<grid, blk, 0, stream>>>(x, W1, hbuf, N, 256, 128);
        coef_kernel<64><<<nodeBlocks, blk, 0, stream>>>(hbuf, a1s, a1d, als, ald, N);
        agg_kernel<64, 0><<<nodeBlocks, blk, 0, stream>>>(hbuf, als, ald, row_off, csr,
                                                          b1, nullptr, x1, N);
    }
    // layer 2
    {
        dim3 grid((N + 127) / 128, 2);
        gemm_kernel<<<grid, blk, 0, stream>>>(x1, W2, hbuf, N, 256, 256);
        coef_kernel<64><<<nodeBlocks, blk, 0, stream>>>(hbuf, a2s, a2d, als, ald, N);
        agg_kernel<64, 1><<<nodeBlocks, blk, 0, stream>>>(hbuf, als, ald, row_off, csr,
                                                          b2, x1, x2, N);
    }
    // layer 3
    {
        dim3 grid((N + 127) / 128, 2);
        gemm_kernel<<<grid, blk, 0, stream>>>(x2, W3, hbuf, N, 160, 256);
        coef_kernel<40><<<nodeBlocks, blk, 0, stream>>>(hbuf, a3s, a3d, als, ald, N);
        agg_kernel<40, 2><<<nodeBlocks, blk, 0, stream>>>(hbuf, als, ald, row_off, csr,
                                                          b3, nullptr, out, N);
    }
}